// Round 6
// baseline (500.801 us; speedup 1.0000x reference)
//
#include <hip/hip_runtime.h>
#include <math.h>

// B=8, Q=4096, C=256, H=8, D=32, L=4, P=4; levels 128/64/32/16 squared.
// R11: vproj restructure. R10 post-mortem: neutral vs R9 despite conflict/fetch
// drops -> bottleneck was per-k-step staging latency (load->wait->write->barrier
// serialization) shared by both. New vproj: A(Wv half, 128x256 bf16) staged ONCE
// per block (528B padded rows: frag reads = 8-cycle b128 minimum); B(feat) loaded
// DIRECTLY global->reg double-buffered (4x64B coalesced segments per instr);
// ZERO barriers in k-loop. 5440 blocks, 2 blocks/CU (LDS 67.6KB).
// ws layout (bytes):
//  sinfo uint2 @0 (33,554,432)
//  guard_lo @33,554,432 (131,072)
//  vbuf bf16 @33,685,504 (89,128,960) -> ends 122,814,464   [gout f32 @33,685,504
//     (50,331,648) lives here between qproj_gemm and setup_kernel]
//  guard_hi @122,814,464 (131,072)
//  preb bf16 @122,945,536 (16,777,216) -> ends 139,722,752
//  wqT bf16[384][256] @139,722,752 | wv bf16[4][256][256] @139,919,360
//  woT bf16[256][256] @140,443,648 -> end 140,574,720 (< proven 148,701,184)

typedef __attribute__((ext_vector_type(8))) short short8_t;
typedef __attribute__((ext_vector_type(4))) short short4_t;
typedef __attribute__((ext_vector_type(4))) float floatx4;

__device__ __forceinline__ float bf2f(unsigned short u) {
    return __uint_as_float(((unsigned int)u) << 16);
}
__device__ __forceinline__ unsigned short f2bf(float f) {
    unsigned int x = __float_as_uint(f);
    unsigned int r = x + 0x7fffu + ((x >> 16) & 1u);
    return (unsigned short)(r >> 16);
}

#define MFMA16(a, b, c) __builtin_amdgcn_mfma_f32_16x16x32_bf16((a), (b), (c), 0, 0, 0)
#define LPAD 40  // LDS row stride in shorts: 80 B = 16B-aligned frags, ~2-way banks (free)

// ---------------- K0: weight prep: cast + transpose to bf16; blocks 56..63 zero guards
__global__ __launch_bounds__(256) void prep_kernel(
    const float* __restrict__ W_off, const float* __restrict__ W_attn,
    const float* __restrict__ Wv0, const float* __restrict__ Wv1,
    const float* __restrict__ Wv2, const float* __restrict__ Wv3,
    const float* __restrict__ W_out,
    unsigned short* __restrict__ wq,
    unsigned short* __restrict__ wv,
    unsigned short* __restrict__ wo,
    uint4* __restrict__ guard_lo,
    uint4* __restrict__ guard_hi)
{
    const int t = threadIdx.x;
    const int blk = blockIdx.x;
    if (blk < 40) {
        __shared__ float tile[64][65];
        int n0, c0, ncols, nbase;
        const float* src;
        unsigned short* dst;
        if (blk < 24) {
            int tt = blk; n0 = (tt >> 2) * 64; c0 = (tt & 3) * 64;
            if (n0 < 256) { src = W_off; ncols = 256; nbase = n0; }
            else          { src = W_attn; ncols = 128; nbase = n0 - 256; }
            dst = wq;
        } else {
            int tt = blk - 24; n0 = (tt >> 2) * 64; c0 = (tt & 3) * 64;
            src = W_out; ncols = 256; nbase = n0; dst = wo;
        }
        for (int i = 0; i < 4; ++i) {
            int idx = i * 256 + t; int c = idx >> 4, n4 = idx & 15;
            float4 v = *(const float4*)&src[(long)(c0 + c) * ncols + nbase + 4 * n4];
            tile[4 * n4 + 0][c] = v.x; tile[4 * n4 + 1][c] = v.y;
            tile[4 * n4 + 2][c] = v.z; tile[4 * n4 + 3][c] = v.w;
        }
        __syncthreads();
        for (int i = 0; i < 4; ++i) {
            int idx = i * 256 + t; int n = idx >> 4, cg = idx & 15;
            short4_t pk;
            pk[0] = (short)f2bf(tile[n][4 * cg + 0]);
            pk[1] = (short)f2bf(tile[n][4 * cg + 1]);
            pk[2] = (short)f2bf(tile[n][4 * cg + 2]);
            pk[3] = (short)f2bf(tile[n][4 * cg + 3]);
            *(short4_t*)&dst[(long)(n0 + n) * 256 + c0 + 4 * cg] = pk;
        }
    } else if (blk < 56) {
        long g0 = (long)(blk - 40) * 16384;
        for (int i = 0; i < 16; ++i) {
            long e = g0 + (long)(i * 256 + t) * 4;
            int l = (int)(e >> 16); int off = (int)(e & 65535);
            const float* s = (l == 0) ? Wv0 : (l == 1) ? Wv1 : (l == 2) ? Wv2 : Wv3;
            float4 v = *(const float4*)&s[off];
            short4_t pk;
            pk[0] = (short)f2bf(v.x); pk[1] = (short)f2bf(v.y);
            pk[2] = (short)f2bf(v.z); pk[3] = (short)f2bf(v.w);
            *(short4_t*)&wv[e] = pk;
        }
    } else {
        // zero 128KB guard zones: 4 blocks each, 32768 B/block = 8 iters x 4096 B
        uint4 z = {0u, 0u, 0u, 0u};
        int sub = (blk - 56) & 3;
        uint4* g = (blk < 60) ? guard_lo : guard_hi;
        g += (long)sub * 2048 + t;   // uint4 units: 32768/16 = 2048 per block
        for (int i = 0; i < 8; ++i) g[i * 256] = z;
    }
}

// ---------------- K1a: qproj GEMM only. M=32768, N=384, K=256 -> gout f32[32768][384]
__global__ __launch_bounds__(256) void qproj_gemm(
    const float* __restrict__ query,
    const unsigned short* __restrict__ wq,
    float* __restrict__ gout)
{
    __shared__ unsigned short aT[64 * LPAD];
    __shared__ unsigned short bT[384 * LPAD];
    const int t = threadIdx.x;
    const int r0 = blockIdx.x * 64;
    const int w = t >> 6, lane = t & 63, quad = lane >> 4, l15 = lane & 15;

    floatx4 acc[24];
#pragma unroll
    for (int i = 0; i < 24; ++i) acc[i] = (floatx4){0.f, 0.f, 0.f, 0.f};

    for (int k0 = 0; k0 < 256; k0 += 32) {
        __syncthreads();
        for (int i = 0; i < 2; ++i) {  // A: query 64x32 fp32 -> bf16 (512 float4)
            int idx = i * 256 + t; int row = idx >> 3, kq = idx & 7;
            float4 v = *(const float4*)&query[(long)(r0 + row) * 256 + k0 + 4 * kq];
            short4_t pk;
            pk[0] = (short)f2bf(v.x); pk[1] = (short)f2bf(v.y);
            pk[2] = (short)f2bf(v.z); pk[3] = (short)f2bf(v.w);
            *(short4_t*)&aT[row * LPAD + 4 * kq] = pk;
        }
        for (int i = 0; i < 6; ++i) {  // B: wqT 384x32 bf16 (1536 uint4)
            int idx = i * 256 + t; int n = idx >> 2, kq = idx & 3;
            uint4 v = *(const uint4*)&wq[(long)n * 256 + k0 + 8 * kq];
            *(uint4*)&bT[n * LPAD + 8 * kq] = v;
        }
        __syncthreads();
        short8_t a8 = *(const short8_t*)&aT[(16 * w + l15) * LPAD + 8 * quad];
#pragma unroll
        for (int j = 0; j < 24; ++j) {
            short8_t b8 = *(const short8_t*)&bT[(16 * j + l15) * LPAD + 8 * quad];
            acc[j] = MFMA16(a8, b8, acc[j]);
        }
    }

    const int rbase = r0 + 16 * w + 4 * quad;
#pragma unroll
    for (int j = 0; j < 24; ++j) {
#pragma unroll
        for (int g = 0; g < 4; ++g)
            gout[(long)(rbase + g) * 384 + 16 * j + l15] = acc[j][g];
    }
}

// ---------------- K1b: setup. 1 thread per (r,h): reg softmax + tanh + pack sinfo.
// sinfo encoding: word0 = u16(i00 signed) | f2bf(X0)<<16
//                 word1 = f2bf(X1) | (wy14 | vy0<<14 | vy1<<15)<<16
// X0=a*(1-wx)*vx0, X1=a*wx*vx1, i00 = rowb + y0*Wl + x0 (unclamped). Fully-invalid
// points emit {0,0} so K3 reads stay within the guarded zones.
__global__ __launch_bounds__(256) void setup_kernel(
    const float* __restrict__ gout, const float* __restrict__ refp,
    const float* __restrict__ b_off, const float* __restrict__ b_attn,
    uint2* __restrict__ sinfo)
{
    const int t = threadIdx.x;
    const int h = t & 7;
    const int r = blockIdx.x * 32 + (t >> 3);
    const float* gl = gout + (long)r * 384;

    // softmax over the 16 attn logits (in registers, no cross-lane ops)
    float a[16];
    float m = -1e30f;
#pragma unroll
    for (int k = 0; k < 16; ++k) {
        a[k] = gl[256 + h * 16 + k] + b_attn[h * 16 + k];
        m = fmaxf(m, a[k]);
    }
    float s = 0.f;
#pragma unroll
    for (int k = 0; k < 16; ++k) { a[k] = __expf(a[k] - m); s += a[k]; }
    const float inv = 1.f / s;

    float off[32];
#pragma unroll
    for (int k = 0; k < 32; ++k) off[k] = gl[h * 32 + k] + b_off[h * 32 + k];
    const float rx = refp[(long)r * 2], ry = refp[(long)r * 2 + 1];

    uint2 pk[16];
#pragma unroll
    for (int k = 0; k < 16; ++k) {
        const int l = k >> 2;
        const int Wl = 128 >> l;
        const float dim1 = (float)(Wl - 1);
        const float scale = 2.0f * (float)(1 << l);
        const int rowb = (l == 0) ? 0 : (l == 1) ? 16384 : (l == 2) ? 20480 : 21504;
        float x = rx * dim1 + tanhf(off[2 * k]) * scale;
        float y = ry * dim1 + tanhf(off[2 * k + 1]) * scale;
        float fx = floorf(x), fy = floorf(y);
        int x0 = (int)fx, y0 = (int)fy;
        float wx = x - fx, wy = y - fy;
        bool vx0 = (x0 >= 0) && (x0 < Wl);
        bool vx1 = (x0 >= -1) && (x0 < Wl - 1);
        bool vy0 = (y0 >= 0) && (y0 < Wl);
        bool vy1 = (y0 >= -1) && (y0 < Wl - 1);
        if ((vx0 | vx1) & (vy0 | vy1)) {
            float av = a[k] * inv;
            float X0 = vx0 ? av * (1.f - wx) : 0.f;
            float X1 = vx1 ? av * wx : 0.f;
            int i00 = rowb + y0 * Wl + x0;           // signed, fits i16
            int wy14 = (int)(wy * 16384.f);          // [0,16383]
            unsigned int ypack = (unsigned int)wy14
                               | (vy0 ? 0x4000u : 0u) | (vy1 ? 0x8000u : 0u);
            pk[k].x = ((unsigned int)i00 & 0xffffu) | ((unsigned int)f2bf(X0) << 16);
            pk[k].y = (unsigned int)f2bf(X1) | (ypack << 16);
        } else {
            pk[k].x = 0u; pk[k].y = 0u;
        }
    }
    uint4* dst = (uint4*)(sinfo + ((long)r * 8 + h) * 16);
    const uint4* src = (const uint4*)pk;
#pragma unroll
    for (int i = 0; i < 8; ++i) dst[i] = src[i];
}

// ---------------- K2: vproj MFMA. Block = 128o x 64s. A(Wv half) staged ONCE into
// LDS (264-short rows = 528B: 16B-aligned, frag reads at b128 minimum cycles).
// B(feat) loaded directly global->reg, double-buffered; NO barriers in k-loop.
// Wave w owns s-strip [s0+16w, s0+16w+16), all 128 o (8 mi), 8 MFMA/k-step.
__global__ __launch_bounds__(256) void vproj_mfma(
    const float* __restrict__ feat0, const float* __restrict__ feat1,
    const float* __restrict__ feat2, const float* __restrict__ feat3,
    const unsigned short* __restrict__ wv,
    const float* __restrict__ bv0, const float* __restrict__ bv1,
    const float* __restrict__ bv2, const float* __restrict__ bv3,
    unsigned short* __restrict__ vbuf)
{
    __shared__ unsigned short aW[128 * 264];   // 67,584 B -> 2 blocks/CU
    const int blk = blockIdx.x;
    const int b = blk / 680;
    const int r = blk % 680;
    const float* feat; const unsigned short* wvl; const float* bvl; int S; long loff; int til;
    if (r < 512)      { til = r;       feat = feat0; wvl = wv;          bvl = bv0; S = 16384; loff = 0; }
    else if (r < 640) { til = r - 512; feat = feat1; wvl = wv + 65536;  bvl = bv1; S = 4096;  loff = 4194304; }
    else if (r < 672) { til = r - 640; feat = feat2; wvl = wv + 131072; bvl = bv2; S = 1024;  loff = 5242880; }
    else              { til = r - 672; feat = feat3; wvl = wv + 196608; bvl = bv3; S = 256;   loff = 5505024; }
    const int s0 = (til >> 1) * 64;
    const int o0 = (til & 1) * 128;
    const long fb = (long)b * 256 * S;
    const int t = threadIdx.x;
    const int w = t >> 6, lane = t & 63, quad = lane >> 4, l15 = lane & 15;

    // ---- stage A once: Wv[o0+o][k] -> aW[o*264 + k]  (4096 uint4, 16/thread)
    for (int i = 0; i < 16; ++i) {
        int idx = i * 256 + t;
        int o = idx >> 5, c8 = idx & 31;
        uint4 v = *(const uint4*)&wvl[(long)(o0 + o) * 256 + 8 * c8];
        *(uint4*)&aW[o * 264 + 8 * c8] = v;
    }
    __syncthreads();

    // ---- k-loop: B direct from global, double-buffered; no barriers
    const long sb = fb + s0 + 16 * w + l15;
    float bcur[8], bnxt[8];
#pragma unroll
    for (int i = 0; i < 8; ++i) bcur[i] = feat[sb + (long)(8 * quad + i) * S];

    floatx4 acc[8];
#pragma unroll
    for (int i = 0; i < 8; ++i) acc[i] = (floatx4){0.f, 0.f, 0.f, 0.f};

    for (int kt = 0; kt < 8; ++kt) {
        if (kt < 7) {
#pragma unroll
            for (int i = 0; i < 8; ++i)
                bnxt[i] = feat[sb + (long)((kt + 1) * 32 + 8 * quad + i) * S];
        }
        short8_t b8;
#pragma unroll
        for (int i = 0; i < 8; ++i) b8[i] = (short)f2bf(bcur[i]);
#pragma unroll
        for (int mi = 0; mi < 8; ++mi) {
            short8_t a8 = *(const short8_t*)&aW[(16 * mi + l15) * 264 + 32 * kt + 8 * quad];
            acc[mi] = MFMA16(a8, b8, acc[mi]);
        }
#pragma unroll
        for (int i = 0; i < 8; ++i) bcur[i] = bnxt[i];
    }

    unsigned short* vb = vbuf + (long)b * 5570560 + loff;
    const int s = s0 + 16 * w + l15;
#pragma unroll
    for (int mi = 0; mi < 8; ++mi) {
        int obase = o0 + 16 * mi + 4 * quad;
        float4 bias = *(const float4*)&bvl[obase];
        short4_t pk;
        pk[0] = (short)f2bf(acc[mi][0] + bias.x);
        pk[1] = (short)f2bf(acc[mi][1] + bias.y);
        pk[2] = (short)f2bf(acc[mi][2] + bias.z);
        pk[3] = (short)f2bf(acc[mi][3] + bias.w);
        *(short4_t*)&vb[(long)s * 256 + obase] = pk;
    }
}

// ---------------- K3: bilinear sampling, precomputed separable weights.
// 4 rows/block; lane owns 4 d-channels -> uint2 gathers (8B, 64B-contig per h-group).
// Stray (zero-weight) reads are bounded to the zeroed guard zones or finite vbuf data.
__global__ __launch_bounds__(256) void sample_kernel(
    const uint2* __restrict__ sinfo,
    const unsigned short* __restrict__ vbuf,
    unsigned short* __restrict__ preb)
{
    const int t = threadIdx.x;
    const int rsub = t >> 6;        // 4 rows per block
    const int h = (t >> 3) & 7;
    const int dq = t & 7;           // d = 4*dq .. 4*dq+3
    const int r = blockIdx.x * 4 + rsub;
    const int b = r >> 12;

    const uint2* info = sinfo + ((long)r * 8 + h) * 16;
    const unsigned short* V = vbuf + (long)b * 5570560 + h * 32 + 4 * dq;

    float o0 = 0.f, o1 = 0.f, o2 = 0.f, o3 = 0.f;
#pragma unroll
    for (int k = 0; k < 16; ++k) {
        const int l = k >> 2;
        const int Wl = 128 >> l;
        uint2 inf = info[k];
        int i00 = (int)(short)(inf.x & 0xffffu);     // sign-extend
        float X0 = __uint_as_float(inf.x & 0xffff0000u);
        float X1 = __uint_as_float(inf.y << 16);
        unsigned int yp = inf.y >> 16;
        float wy = (float)(yp & 0x3fffu) * (1.f / 16384.f);
        float Y1 = (yp & 0x8000u) ? wy : 0.f;
        float Y0 = (yp & 0x4000u) ? (1.f - wy) : 0.f;
        const unsigned short* b00 = V + (long)i00 * 256;
        const unsigned short* b10 = b00 + Wl * 256;
        uint2 g00 = *(const uint2*)(b00);
        uint2 g01 = *(const uint2*)(b00 + 256);
        uint2 g10 = *(const uint2*)(b10);
        uint2 g11 = *(const uint2*)(b10 + 256);
        float aw00 = X0 * Y0, aw01 = X1 * Y0, aw10 = X0 * Y1, aw11 = X1 * Y1;
        o0 += __uint_as_float(g00.x << 16) * aw00 + __uint_as_float(g01.x << 16) * aw01
            + __uint_as_float(g10.x << 16) * aw10 + __uint_as_float(g11.x << 16) * aw11;
        o1 += __uint_as_float(g00.x & 0xffff0000u) * aw00 + __uint_as_float(g01.x & 0xffff0000u) * aw01
            + __uint_as_float(g10.x & 0xffff0000u) * aw10 + __uint_as_float(g11.x & 0xffff0000u) * aw11;
        o2 += __uint_as_float(g00.y << 16) * aw00 + __uint_as_float(g01.y << 16) * aw01
            + __uint_as_float(g10.y << 16) * aw10 + __uint_as_float(g11.y << 16) * aw11;
        o3 += __uint_as_float(g00.y & 0xffff0000u) * aw00 + __uint_as_float(g01.y & 0xffff0000u) * aw01
            + __uint_as_float(g10.y & 0xffff0000u) * aw10 + __uint_as_float(g11.y & 0xffff0000u) * aw11;
    }
    short4_t pk;
    pk[0] = (short)f2bf(o0); pk[1] = (short)f2bf(o1);
    pk[2] = (short)f2bf(o2); pk[3] = (short)f2bf(o3);
    *(short4_t*)&preb[(long)r * 256 + h * 32 + 4 * dq] = pk;
}

// ---------------- K4: outproj MFMA. D[j][r]; coalesced float4 stores.
__global__ __launch_bounds__(256) void outproj_mfma(
    const unsigned short* __restrict__ preb,
    const unsigned short* __restrict__ wo,
    const float* __restrict__ b_out,
    float* __restrict__ out)
{
    __shared__ unsigned short aJ[256 * LPAD];
    __shared__ unsigned short bR[64 * LPAD];
    const int t = threadIdx.x;
    const int r0 = blockIdx.x * 64;
    const int w = t >> 6, lane = t & 63, quad = lane >> 4, l15 = lane & 15;

    floatx4 acc[4][4];
#pragma unroll
    for (int i = 0; i < 4; ++i)
#pragma unroll
        for (int j = 0; j < 4; ++j) acc[i][j] = (floatx4){0.f, 0.f, 0.f, 0.f};

    for (int k0 = 0; k0 < 256; k0 += 32) {
        __syncthreads();
        for (int i = 0; i < 4; ++i) {  // A: woT 256 rows x 32k = 1024 uint4
            int idx = i * 256 + t; int j = idx >> 2, kq = idx & 3;
            uint4 v = *(const uint4*)&wo[(long)j * 256 + k0 + 8 * kq];
            *(uint4*)&aJ[j * LPAD + 8 * kq] = v;
        }
        {   // B: preb 64 rows x 32k = 256 uint4
            int rr = t >> 2, kq = t & 3;
            uint4 v = *(const uint4*)&preb[(long)(r0 + rr) * 256 + k0 + 8 * kq];
            *(uint4*)&bR[rr * LPAD + 8 * kq] = v;
        }
        __syncthreads();
        short8_t am[4];
#pragma unroll
        for (int mi = 0; mi < 4; ++mi)
            am[mi] = *(const short8_t*)&aJ[(64 * w + 16 * mi + l15) * LPAD + 8 * quad];
#pragma unroll
        for (int nj = 0; nj < 4; ++nj) {
            short8_t b8 = *(const short8_t*)&bR[(16 * nj + l15) * LPAD + 8 * quad];
#pragma unroll
            for (int mi = 0; mi < 4; ++mi)
                acc[mi][nj] = MFMA16(am[mi], b8, acc[mi][nj]);
        }
    }

#pragma unroll
    for (int mi = 0; mi < 4; ++mi) {
        int j0 = 64 * w + 16 * mi + 4 * quad;
        float4 bias = *(const float4*)&b_out[j0];
#pragma unroll
        for (int nj = 0; nj < 4; ++nj) {
            int r = r0 + 16 * nj + l15;
            float4 res;
            res.x = acc[mi][nj][0] + bias.x;
            res.y = acc[mi][nj][1] + bias.y;
            res.z = acc[mi][nj][2] + bias.z;
            res.w = acc[mi][nj][3] + bias.w;
            *(float4*)&out[(long)r * 256 + j0] = res;
        }
    }
}

extern "C" void kernel_launch(void* const* d_in, const int* in_sizes, int n_in,
                              void* d_out, int out_size, void* d_ws, size_t ws_size,
                              hipStream_t stream) {
    const float* query  = (const float*)d_in[0];
    const float* refp   = (const float*)d_in[1];
    const float* feat0  = (const float*)d_in[2];
    const float* feat1  = (const float*)d_in[3];
    const float* feat2  = (const float*)d_in[4];
    const float* feat3  = (const float*)d_in[5];
    const float* W_off  = (const float*)d_in[6];
    const float* b_off  = (const float*)d_in[7];
    const float* W_attn = (const float*)d_in[8];
    const float* b_attn = (const float*)d_in[9];
    const float* Wv0 = (const float*)d_in[10]; const float* bv0 = (const float*)d_in[11];
    const float* Wv1 = (const float*)d_in[12]; const float* bv1 = (const float*)d_in[13];
    const float* Wv2 = (const float*)d_in[14]; const float* bv2 = (const float*)d_in[15];
    const float* Wv3 = (const float*)d_in[16]; const float* bv3 = (const float*)d_in[17];
    const float* W_out = (const float*)d_in[18]; const float* b_out = (const float*)d_in[19];
    float* out = (float*)d_out;

    char* ws = (char*)d_ws;
    uint2*          sinfo = (uint2*)(ws + 0);
    uint4*          guard_lo = (uint4*)(ws + 33554432);
    unsigned short* vbuf = (unsigned short*)(ws + 33685504);
    float*          gout = (float*)(ws + 33685504);   // overlaps vbuf (dead until vproj)
    uint4*          guard_hi = (uint4*)(ws + 122814464);
    unsigned short* preb = (unsigned short*)(ws + 122945536);
    unsigned short* wq   = (unsigned short*)(ws + 139722752);
    unsigned short* wv   = (unsigned short*)(ws + 139919360);
    unsigned short* wo   = (unsigned short*)(ws + 140443648);

    prep_kernel<<<64, 256, 0, stream>>>(W_off, W_attn, Wv0, Wv1, Wv2, Wv3, W_out,
                                        wq, wv, wo, guard_lo, guard_hi);
    qproj_gemm<<<512, 256, 0, stream>>>(query, wq, gout);
    setup_kernel<<<1024, 256, 0, stream>>>(gout, refp, b_off, b_attn, sinfo);
    vproj_mfma<<<5440, 256, 0, stream>>>(feat0, feat1, feat2, feat3, wv,
                                         bv0, bv1, bv2, bv3, vbuf);
    sample_kernel<<<8192, 256, 0, stream>>>(sinfo, vbuf, preb);
    outproj_mfma<<<512, 256, 0, stream>>>(preb, wo, b_out, out);
}

// Round 9
// 484.771 us; speedup vs baseline: 1.0331x; 1.0331x over previous
//
#include <hip/hip_runtime.h>
#include <math.h>

// B=8, Q=4096, C=256, H=8, D=32, L=4, P=4; levels 128/64/32/16 squared.
// R14: occupancy via 512-thread blocks on R11's proven structure. R12/R13 (zero-LDS
// vproj + launch_bounds(256,4)) killed the container twice -> abandoned. Same
// hypothesis (vproj latency-bound at 21% occupancy), safe implementation:
// vproj tile 128o x 128s, 512 threads (8 waves), LDS 67.5KB unchanged -> still
// 2 blocks/CU but 16 waves/CU (~50% occ, 2x R11). A(Wv) staged once; feat
// global->reg 1-step prefetch; zero k-loop barriers. feat read 2x (o-halves) but
// all feats (178MB) fit L3 -> no extra HBM. Grid 2720.
// ws layout (bytes):
//  sinfo uint2 @0 (33,554,432)
//  guard_lo @33,554,432 (131,072)
//  vbuf bf16 @33,685,504 (89,128,960) -> ends 122,814,464   [gout f32 @33,685,504
//     (50,331,648) lives here between qproj_gemm and setup_kernel]
//  guard_hi @122,814,464 (131,072)
//  preb bf16 @122,945,536 (16,777,216) -> ends 139,722,752
//  wqT bf16[384][256] @139,722,752 | wv bf16[4][256][256] @139,919,360
//  woT bf16[256][256] @140,443,648 -> end 140,574,720 (< proven 148,701,184)

typedef __attribute__((ext_vector_type(8))) short short8_t;
typedef __attribute__((ext_vector_type(4))) short short4_t;
typedef __attribute__((ext_vector_type(4))) float floatx4;

__device__ __forceinline__ float bf2f(unsigned short u) {
    return __uint_as_float(((unsigned int)u) << 16);
}
__device__ __forceinline__ unsigned short f2bf(float f) {
    unsigned int x = __float_as_uint(f);
    unsigned int r = x + 0x7fffu + ((x >> 16) & 1u);
    return (unsigned short)(r >> 16);
}

#define MFMA16(a, b, c) __builtin_amdgcn_mfma_f32_16x16x32_bf16((a), (b), (c), 0, 0, 0)
#define LPAD 40  // LDS row stride in shorts: 80 B = 16B-aligned frags, ~2-way banks (free)

// ---------------- K0: weight prep: cast + transpose to bf16; blocks 56..63 zero guards
__global__ __launch_bounds__(256) void prep_kernel(
    const float* __restrict__ W_off, const float* __restrict__ W_attn,
    const float* __restrict__ Wv0, const float* __restrict__ Wv1,
    const float* __restrict__ Wv2, const float* __restrict__ Wv3,
    const float* __restrict__ W_out,
    unsigned short* __restrict__ wq,
    unsigned short* __restrict__ wv,
    unsigned short* __restrict__ wo,
    uint4* __restrict__ guard_lo,
    uint4* __restrict__ guard_hi)
{
    const int t = threadIdx.x;
    const int blk = blockIdx.x;
    if (blk < 40) {
        __shared__ float tile[64][65];
        int n0, c0, ncols, nbase;
        const float* src;
        unsigned short* dst;
        if (blk < 24) {
            int tt = blk; n0 = (tt >> 2) * 64; c0 = (tt & 3) * 64;
            if (n0 < 256) { src = W_off; ncols = 256; nbase = n0; }
            else          { src = W_attn; ncols = 128; nbase = n0 - 256; }
            dst = wq;
        } else {
            int tt = blk - 24; n0 = (tt >> 2) * 64; c0 = (tt & 3) * 64;
            src = W_out; ncols = 256; nbase = n0; dst = wo;
        }
        for (int i = 0; i < 4; ++i) {
            int idx = i * 256 + t; int c = idx >> 4, n4 = idx & 15;
            float4 v = *(const float4*)&src[(long)(c0 + c) * ncols + nbase + 4 * n4];
            tile[4 * n4 + 0][c] = v.x; tile[4 * n4 + 1][c] = v.y;
            tile[4 * n4 + 2][c] = v.z; tile[4 * n4 + 3][c] = v.w;
        }
        __syncthreads();
        for (int i = 0; i < 4; ++i) {
            int idx = i * 256 + t; int n = idx >> 4, cg = idx & 15;
            short4_t pk;
            pk[0] = (short)f2bf(tile[n][4 * cg + 0]);
            pk[1] = (short)f2bf(tile[n][4 * cg + 1]);
            pk[2] = (short)f2bf(tile[n][4 * cg + 2]);
            pk[3] = (short)f2bf(tile[n][4 * cg + 3]);
            *(short4_t*)&dst[(long)(n0 + n) * 256 + c0 + 4 * cg] = pk;
        }
    } else if (blk < 56) {
        long g0 = (long)(blk - 40) * 16384;
        for (int i = 0; i < 16; ++i) {
            long e = g0 + (long)(i * 256 + t) * 4;
            int l = (int)(e >> 16); int off = (int)(e & 65535);
            const float* s = (l == 0) ? Wv0 : (l == 1) ? Wv1 : (l == 2) ? Wv2 : Wv3;
            float4 v = *(const float4*)&s[off];
            short4_t pk;
            pk[0] = (short)f2bf(v.x); pk[1] = (short)f2bf(v.y);
            pk[2] = (short)f2bf(v.z); pk[3] = (short)f2bf(v.w);
            *(short4_t*)&wv[e] = pk;
        }
    } else {
        // zero 128KB guard zones: 4 blocks each, 32768 B/block = 8 iters x 4096 B
        uint4 z = {0u, 0u, 0u, 0u};
        int sub = (blk - 56) & 3;
        uint4* g = (blk < 60) ? guard_lo : guard_hi;
        g += (long)sub * 2048 + t;   // uint4 units: 32768/16 = 2048 per block
        for (int i = 0; i < 8; ++i) g[i * 256] = z;
    }
}

// ---------------- K1a: qproj GEMM only. M=32768, N=384, K=256 -> gout f32[32768][384]
__global__ __launch_bounds__(256) void qproj_gemm(
    const float* __restrict__ query,
    const unsigned short* __restrict__ wq,
    float* __restrict__ gout)
{
    __shared__ unsigned short aT[64 * LPAD];
    __shared__ unsigned short bT[384 * LPAD];
    const int t = threadIdx.x;
    const int r0 = blockIdx.x * 64;
    const int w = t >> 6, lane = t & 63, quad = lane >> 4, l15 = lane & 15;

    floatx4 acc[24];
#pragma unroll
    for (int i = 0; i < 24; ++i) acc[i] = (floatx4){0.f, 0.f, 0.f, 0.f};

    for (int k0 = 0; k0 < 256; k0 += 32) {
        __syncthreads();
        for (int i = 0; i < 2; ++i) {  // A: query 64x32 fp32 -> bf16 (512 float4)
            int idx = i * 256 + t; int row = idx >> 3, kq = idx & 7;
            float4 v = *(const float4*)&query[(long)(r0 + row) * 256 + k0 + 4 * kq];
            short4_t pk;
            pk[0] = (short)f2bf(v.x); pk[1] = (short)f2bf(v.y);
            pk[2] = (short)f2bf(v.z); pk[3] = (short)f2bf(v.w);
            *(short4_t*)&aT[row * LPAD + 4 * kq] = pk;
        }
        for (int i = 0; i < 6; ++i) {  // B: wqT 384x32 bf16 (1536 uint4)
            int idx = i * 256 + t; int n = idx >> 2, kq = idx & 3;
            uint4 v = *(const uint4*)&wq[(long)n * 256 + k0 + 8 * kq];
            *(uint4*)&bT[n * LPAD + 8 * kq] = v;
        }
        __syncthreads();
        short8_t a8 = *(const short8_t*)&aT[(16 * w + l15) * LPAD + 8 * quad];
#pragma unroll
        for (int j = 0; j < 24; ++j) {
            short8_t b8 = *(const short8_t*)&bT[(16 * j + l15) * LPAD + 8 * quad];
            acc[j] = MFMA16(a8, b8, acc[j]);
        }
    }

    const int rbase = r0 + 16 * w + 4 * quad;
#pragma unroll
    for (int j = 0; j < 24; ++j) {
#pragma unroll
        for (int g = 0; g < 4; ++g)
            gout[(long)(rbase + g) * 384 + 16 * j + l15] = acc[j][g];
    }
}

// ---------------- K1b: setup. 1 thread per (r,h): reg softmax + tanh + pack sinfo.
// sinfo encoding: word0 = u16(i00 signed) | f2bf(X0)<<16
//                 word1 = f2bf(X1) | (wy14 | vy0<<14 | vy1<<15)<<16
// X0=a*(1-wx)*vx0, X1=a*wx*vx1, i00 = rowb + y0*Wl + x0 (unclamped). Fully-invalid
// points emit {0,0} so K3 reads stay within the guarded zones.
__global__ __launch_bounds__(256) void setup_kernel(
    const float* __restrict__ gout, const float* __restrict__ refp,
    const float* __restrict__ b_off, const float* __restrict__ b_attn,
    uint2* __restrict__ sinfo)
{
    const int t = threadIdx.x;
    const int h = t & 7;
    const int r = blockIdx.x * 32 + (t >> 3);
    const float* gl = gout + (long)r * 384;

    // softmax over the 16 attn logits (in registers, no cross-lane ops)
    float a[16];
    float m = -1e30f;
#pragma unroll
    for (int k = 0; k < 16; ++k) {
        a[k] = gl[256 + h * 16 + k] + b_attn[h * 16 + k];
        m = fmaxf(m, a[k]);
    }
    float s = 0.f;
#pragma unroll
    for (int k = 0; k < 16; ++k) { a[k] = __expf(a[k] - m); s += a[k]; }
    const float inv = 1.f / s;

    float off[32];
#pragma unroll
    for (int k = 0; k < 32; ++k) off[k] = gl[h * 32 + k] + b_off[h * 32 + k];
    const float rx = refp[(long)r * 2], ry = refp[(long)r * 2 + 1];

    uint2 pk[16];
#pragma unroll
    for (int k = 0; k < 16; ++k) {
        const int l = k >> 2;
        const int Wl = 128 >> l;
        const float dim1 = (float)(Wl - 1);
        const float scale = 2.0f * (float)(1 << l);
        const int rowb = (l == 0) ? 0 : (l == 1) ? 16384 : (l == 2) ? 20480 : 21504;
        float x = rx * dim1 + tanhf(off[2 * k]) * scale;
        float y = ry * dim1 + tanhf(off[2 * k + 1]) * scale;
        float fx = floorf(x), fy = floorf(y);
        int x0 = (int)fx, y0 = (int)fy;
        float wx = x - fx, wy = y - fy;
        bool vx0 = (x0 >= 0) && (x0 < Wl);
        bool vx1 = (x0 >= -1) && (x0 < Wl - 1);
        bool vy0 = (y0 >= 0) && (y0 < Wl);
        bool vy1 = (y0 >= -1) && (y0 < Wl - 1);
        if ((vx0 | vx1) & (vy0 | vy1)) {
            float av = a[k] * inv;
            float X0 = vx0 ? av * (1.f - wx) : 0.f;
            float X1 = vx1 ? av * wx : 0.f;
            int i00 = rowb + y0 * Wl + x0;           // signed, fits i16
            int wy14 = (int)(wy * 16384.f);          // [0,16383]
            unsigned int ypack = (unsigned int)wy14
                               | (vy0 ? 0x4000u : 0u) | (vy1 ? 0x8000u : 0u);
            pk[k].x = ((unsigned int)i00 & 0xffffu) | ((unsigned int)f2bf(X0) << 16);
            pk[k].y = (unsigned int)f2bf(X1) | (ypack << 16);
        } else {
            pk[k].x = 0u; pk[k].y = 0u;
        }
    }
    uint4* dst = (uint4*)(sinfo + ((long)r * 8 + h) * 16);
    const uint4* src = (const uint4*)pk;
#pragma unroll
    for (int i = 0; i < 8; ++i) dst[i] = src[i];
}

// ---------------- K2: vproj MFMA. 512 threads (8 waves), tile 128o x 128s.
// A(Wv half) staged ONCE into LDS (264-short rows = 528B, 16B-aligned). B(feat)
// global->reg 1-step prefetch. NO barriers in k-loop. 2 blocks/CU x 8 waves =
// 16 waves/CU (~50% occupancy, 2x R11). Wave w owns s-strip [s0+16w, s0+16w+16).
__global__ __launch_bounds__(512) void vproj_mfma(
    const float* __restrict__ feat0, const float* __restrict__ feat1,
    const float* __restrict__ feat2, const float* __restrict__ feat3,
    const unsigned short* __restrict__ wv,
    const float* __restrict__ bv0, const float* __restrict__ bv1,
    const float* __restrict__ bv2, const float* __restrict__ bv3,
    unsigned short* __restrict__ vbuf)
{
    __shared__ unsigned short aW[128 * 264];   // 67,584 B
    const int blk = blockIdx.x;
    const int b = blk / 340;
    const int r = blk % 340;
    const float* feat; const unsigned short* wvl; const float* bvl; int S; long loff; int til;
    if (r < 256)      { til = r;       feat = feat0; wvl = wv;          bvl = bv0; S = 16384; loff = 0; }
    else if (r < 320) { til = r - 256; feat = feat1; wvl = wv + 65536;  bvl = bv1; S = 4096;  loff = 4194304; }
    else if (r < 336) { til = r - 320; feat = feat2; wvl = wv + 131072; bvl = bv2; S = 1024;  loff = 5242880; }
    else              { til = r - 336; feat = feat3; wvl = wv + 196608; bvl = bv3; S = 256;   loff = 5505024; }
    const int s0 = (til >> 1) * 128;
    const int o0 = (til & 1) * 128;
    const long fb = (long)b * 256 * S;
    const int t = threadIdx.x;
    const int w = t >> 6, lane = t & 63, quad = lane >> 4, l15 = lane & 15;

    // ---- stage A once: Wv[o0+o][k] -> aW[o*264 + k]  (4096 uint4, 8/thread)
    for (int i = 0; i < 8; ++i) {
        int idx = i * 512 + t;
        int o = idx >> 5, c8 = idx & 31;
        uint4 v = *(const uint4*)&wvl[(long)(o0 + o) * 256 + 8 * c8];
        *(uint4*)&aW[o * 264 + 8 * c8] = v;
    }
    __syncthreads();

    // ---- k-loop: B direct from global, double-buffered; no barriers
    const long sb = fb + s0 + 16 * w + l15;
    float bcur[8], bnxt[8];
#pragma unroll
    for (int i = 0; i < 8; ++i) bcur[i] = feat[sb + (long)(8 * quad + i) * S];

    floatx4 acc[8];
#pragma unroll
    for (int i = 0; i < 8; ++i) acc[i] = (floatx4){0.f, 0.f, 0.f, 0.f};

    for (int kt = 0; kt < 8; ++kt) {
        if (kt < 7) {
#pragma unroll
            for (int i = 0; i < 8; ++i)
                bnxt[i] = feat[sb + (long)((kt + 1) * 32 + 8 * quad + i) * S];
        }
        short8_t b8;
#pragma unroll
        for (int i = 0; i < 8; ++i) b8[i] = (short)f2bf(bcur[i]);
#pragma unroll
        for (int mi = 0; mi < 8; ++mi) {
            short8_t a8 = *(const short8_t*)&aW[(16 * mi + l15) * 264 + 32 * kt + 8 * quad];
            acc[mi] = MFMA16(a8, b8, acc[mi]);
        }
#pragma unroll
        for (int i = 0; i < 8; ++i) bcur[i] = bnxt[i];
    }

    unsigned short* vb = vbuf + (long)b * 5570560 + loff;
    const int s = s0 + 16 * w + l15;
#pragma unroll
    for (int mi = 0; mi < 8; ++mi) {
        int obase = o0 + 16 * mi + 4 * quad;
        float4 bias = *(const float4*)&bvl[obase];
        short4_t pk;
        pk[0] = (short)f2bf(acc[mi][0] + bias.x);
        pk[1] = (short)f2bf(acc[mi][1] + bias.y);
        pk[2] = (short)f2bf(acc[mi][2] + bias.z);
        pk[3] = (short)f2bf(acc[mi][3] + bias.w);
        *(short4_t*)&vb[(long)s * 256 + obase] = pk;
    }
}

// ---------------- K3: bilinear sampling, precomputed separable weights.
// 4 rows/block; lane owns 4 d-channels -> uint2 gathers (8B, 64B-contig per h-group).
// Stray (zero-weight) reads are bounded to the zeroed guard zones or finite vbuf data.
__global__ __launch_bounds__(256) void sample_kernel(
    const uint2* __restrict__ sinfo,
    const unsigned short* __restrict__ vbuf,
    unsigned short* __restrict__ preb)
{
    const int t = threadIdx.x;
    const int rsub = t >> 6;        // 4 rows per block
    const int h = (t >> 3) & 7;
    const int dq = t & 7;           // d = 4*dq .. 4*dq+3
    const int r = blockIdx.x * 4 + rsub;
    const int b = r >> 12;

    const uint2* info = sinfo + ((long)r * 8 + h) * 16;
    const unsigned short* V = vbuf + (long)b * 5570560 + h * 32 + 4 * dq;

    float o0 = 0.f, o1 = 0.f, o2 = 0.f, o3 = 0.f;
#pragma unroll
    for (int k = 0; k < 16; ++k) {
        const int l = k >> 2;
        const int Wl = 128 >> l;
        uint2 inf = info[k];
        int i00 = (int)(short)(inf.x & 0xffffu);     // sign-extend
        float X0 = __uint_as_float(inf.x & 0xffff0000u);
        float X1 = __uint_as_float(inf.y << 16);
        unsigned int yp = inf.y >> 16;
        float wy = (float)(yp & 0x3fffu) * (1.f / 16384.f);
        float Y1 = (yp & 0x8000u) ? wy : 0.f;
        float Y0 = (yp & 0x4000u) ? (1.f - wy) : 0.f;
        const unsigned short* b00 = V + (long)i00 * 256;
        const unsigned short* b10 = b00 + Wl * 256;
        uint2 g00 = *(const uint2*)(b00);
        uint2 g01 = *(const uint2*)(b00 + 256);
        uint2 g10 = *(const uint2*)(b10);
        uint2 g11 = *(const uint2*)(b10 + 256);
        float aw00 = X0 * Y0, aw01 = X1 * Y0, aw10 = X0 * Y1, aw11 = X1 * Y1;
        o0 += __uint_as_float(g00.x << 16) * aw00 + __uint_as_float(g01.x << 16) * aw01
            + __uint_as_float(g10.x << 16) * aw10 + __uint_as_float(g11.x << 16) * aw11;
        o1 += __uint_as_float(g00.x & 0xffff0000u) * aw00 + __uint_as_float(g01.x & 0xffff0000u) * aw01
            + __uint_as_float(g10.x & 0xffff0000u) * aw10 + __uint_as_float(g11.x & 0xffff0000u) * aw11;
        o2 += __uint_as_float(g00.y << 16) * aw00 + __uint_as_float(g01.y << 16) * aw01
            + __uint_as_float(g10.y << 16) * aw10 + __uint_as_float(g11.y << 16) * aw11;
        o3 += __uint_as_float(g00.y & 0xffff0000u) * aw00 + __uint_as_float(g01.y & 0xffff0000u) * aw01
            + __uint_as_float(g10.y & 0xffff0000u) * aw10 + __uint_as_float(g11.y & 0xffff0000u) * aw11;
    }
    short4_t pk;
    pk[0] = (short)f2bf(o0); pk[1] = (short)f2bf(o1);
    pk[2] = (short)f2bf(o2); pk[3] = (short)f2bf(o3);
    *(short4_t*)&preb[(long)r * 256 + h * 32 + 4 * dq] = pk;
}

// ---------------- K4: outproj MFMA. D[j][r]; coalesced float4 stores.
__global__ __launch_bounds__(256) void outproj_mfma(
    const unsigned short* __restrict__ preb,
    const unsigned short* __restrict__ wo,
    const float* __restrict__ b_out,
    float* __restrict__ out)
{
    __shared__ unsigned short aJ[256 * LPAD];
    __shared__ unsigned short bR[64 * LPAD];
    const int t = threadIdx.x;
    const int r0 = blockIdx.x * 64;
    const int w = t >> 6, lane = t & 63, quad = lane >> 4, l15 = lane & 15;

    floatx4 acc[4][4];
#pragma unroll
    for (int i = 0; i < 4; ++i)
#pragma unroll
        for (int j = 0; j < 4; ++j) acc[i][j] = (floatx4){0.f, 0.f, 0.f, 0.f};

    for (int k0 = 0; k0 < 256; k0 += 32) {
        __syncthreads();
        for (int i = 0; i < 4; ++i) {  // A: woT 256 rows x 32k = 1024 uint4
            int idx = i * 256 + t; int j = idx >> 2, kq = idx & 3;
            uint4 v = *(const uint4*)&wo[(long)j * 256 + k0 + 8 * kq];
            *(uint4*)&aJ[j * LPAD + 8 * kq] = v;
        }
        {   // B: preb 64 rows x 32k = 256 uint4
            int rr = t >> 2, kq = t & 3;
            uint4 v = *(const uint4*)&preb[(long)(r0 + rr) * 256 + k0 + 8 * kq];
            *(uint4*)&bR[rr * LPAD + 8 * kq] = v;
        }
        __syncthreads();
        short8_t am[4];
#pragma unroll
        for (int mi = 0; mi < 4; ++mi)
            am[mi] = *(const short8_t*)&aJ[(64 * w + 16 * mi + l15) * LPAD + 8 * quad];
#pragma unroll
        for (int nj = 0; nj < 4; ++nj) {
            short8_t b8 = *(const short8_t*)&bR[(16 * nj + l15) * LPAD + 8 * quad];
#pragma unroll
            for (int mi = 0; mi < 4; ++mi)
                acc[mi][nj] = MFMA16(am[mi], b8, acc[mi][nj]);
        }
    }

#pragma unroll
    for (int mi = 0; mi < 4; ++mi) {
        int j0 = 64 * w + 16 * mi + 4 * quad;
        float4 bias = *(const float4*)&b_out[j0];
#pragma unroll
        for (int nj = 0; nj < 4; ++nj) {
            int r = r0 + 16 * nj + l15;
            float4 res;
            res.x = acc[mi][nj][0] + bias.x;
            res.y = acc[mi][nj][1] + bias.y;
            res.z = acc[mi][nj][2] + bias.z;
            res.w = acc[mi][nj][3] + bias.w;
            *(float4*)&out[(long)r * 256 + j0] = res;
        }
    }
}

extern "C" void kernel_launch(void* const* d_in, const int* in_sizes, int n_in,
                              void* d_out, int out_size, void* d_ws, size_t ws_size,
                              hipStream_t stream) {
    const float* query  = (const float*)d_in[0];
    const float* refp   = (const float*)d_in[1];
    const float* feat0  = (const float*)d_in[2];
    const float* feat1  = (const float*)d_in[3];
    const float* feat2  = (const float*)d_in[4];
    const float* feat3  = (const float*)d_in[5];
    const float* W_off  = (const float*)d_in[6];
    const float* b_off  = (const float*)d_in[7];
    const float* W_attn = (const float*)d_in[8];
    const float* b_attn = (const float*)d_in[9];
    const float* Wv0 = (const float*)d_in[10]; const float* bv0 = (const float*)d_in[11];
    const float* Wv1 = (const float*)d_in[12]; const float* bv1 = (const float*)d_in[13];
    const float* Wv2 = (const float*)d_in[14]; const float* bv2 = (const float*)d_in[15];
    const float* Wv3 = (const float*)d_in[16]; const float* bv3 = (const float*)d_in[17];
    const float* W_out = (const float*)d_in[18]; const float* b_out = (const float*)d_in[19];
    float* out = (float*)d_out;

    char* ws = (char*)d_ws;
    uint2*          sinfo = (uint2*)(ws + 0);
    uint4*          guard_lo = (uint4*)(ws + 33554432);
    unsigned short* vbuf = (unsigned short*)(ws + 33685504);
    float*          gout = (float*)(ws + 33685504);   // overlaps vbuf (dead until vproj)
    uint4*          guard_hi = (uint4*)(ws + 122814464);
    unsigned short* preb = (unsigned short*)(ws + 122945536);
    unsigned short* wq   = (unsigned short*)(ws + 139722752);
    unsigned short* wv   = (unsigned short*)(ws + 139919360);
    unsigned short* wo   = (unsigned short*)(ws + 140443648);

    prep_kernel<<<64, 256, 0, stream>>>(W_off, W_attn, Wv0, Wv1, Wv2, Wv3, W_out,
                                        wq, wv, wo, guard_lo, guard_hi);
    qproj_gemm<<<512, 256, 0, stream>>>(query, wq, gout);
    setup_kernel<<<1024, 256, 0, stream>>>(gout, refp, b_off, b_attn, sinfo);
    vproj_mfma<<<2720, 512, 0, stream>>>(feat0, feat1, feat2, feat3, wv,
                                         bv0, bv1, bv2, bv3, vbuf);
    sample_kernel<<<8192, 256, 0, stream>>>(sinfo, vbuf, preb);
    outproj_mfma<<<512, 256, 0, stream>>>(preb, wo, b_out, out);
}

// Round 10
// 474.492 us; speedup vs baseline: 1.0554x; 1.0217x over previous
//
#include <hip/hip_runtime.h>
#include <math.h>

// B=8, Q=4096, C=256, H=8, D=32, L=4, P=4; levels 128/64/32/16 squared.
// R15: (1) vproj tile 128o x 256s — each wave owns TWO s-strips sharing one a8
// LDS read -> 16 MFMA + 16 loads per k-step per wave (2x R14's latency cover);
// LDS unchanged 67.5KB, grid 1360. (2) sample uint4 gathers (8 d/lane, 4 lanes/h):
// half the gather instructions, 128B per 4-lane tap; grid 4096.
// ws layout (bytes):
//  sinfo uint2 @0 (33,554,432)
//  guard_lo @33,554,432 (131,072)
//  vbuf bf16 @33,685,504 (89,128,960) -> ends 122,814,464   [gout f32 @33,685,504
//     (50,331,648) lives here between qproj_gemm and setup_kernel]
//  guard_hi @122,814,464 (131,072)
//  preb bf16 @122,945,536 (16,777,216) -> ends 139,722,752
//  wqT bf16[384][256] @139,722,752 | wv bf16[4][256][256] @139,919,360
//  woT bf16[256][256] @140,443,648 -> end 140,574,720 (< proven 148,701,184)

typedef __attribute__((ext_vector_type(8))) short short8_t;
typedef __attribute__((ext_vector_type(4))) short short4_t;
typedef __attribute__((ext_vector_type(4))) float floatx4;

__device__ __forceinline__ float bf2f(unsigned short u) {
    return __uint_as_float(((unsigned int)u) << 16);
}
__device__ __forceinline__ unsigned short f2bf(float f) {
    unsigned int x = __float_as_uint(f);
    unsigned int r = x + 0x7fffu + ((x >> 16) & 1u);
    return (unsigned short)(r >> 16);
}

#define MFMA16(a, b, c) __builtin_amdgcn_mfma_f32_16x16x32_bf16((a), (b), (c), 0, 0, 0)
#define LPAD 40  // LDS row stride in shorts: 80 B = 16B-aligned frags, ~2-way banks (free)

// ---------------- K0: weight prep: cast + transpose to bf16; blocks 56..63 zero guards
__global__ __launch_bounds__(256) void prep_kernel(
    const float* __restrict__ W_off, const float* __restrict__ W_attn,
    const float* __restrict__ Wv0, const float* __restrict__ Wv1,
    const float* __restrict__ Wv2, const float* __restrict__ Wv3,
    const float* __restrict__ W_out,
    unsigned short* __restrict__ wq,
    unsigned short* __restrict__ wv,
    unsigned short* __restrict__ wo,
    uint4* __restrict__ guard_lo,
    uint4* __restrict__ guard_hi)
{
    const int t = threadIdx.x;
    const int blk = blockIdx.x;
    if (blk < 40) {
        __shared__ float tile[64][65];
        int n0, c0, ncols, nbase;
        const float* src;
        unsigned short* dst;
        if (blk < 24) {
            int tt = blk; n0 = (tt >> 2) * 64; c0 = (tt & 3) * 64;
            if (n0 < 256) { src = W_off; ncols = 256; nbase = n0; }
            else          { src = W_attn; ncols = 128; nbase = n0 - 256; }
            dst = wq;
        } else {
            int tt = blk - 24; n0 = (tt >> 2) * 64; c0 = (tt & 3) * 64;
            src = W_out; ncols = 256; nbase = n0; dst = wo;
        }
        for (int i = 0; i < 4; ++i) {
            int idx = i * 256 + t; int c = idx >> 4, n4 = idx & 15;
            float4 v = *(const float4*)&src[(long)(c0 + c) * ncols + nbase + 4 * n4];
            tile[4 * n4 + 0][c] = v.x; tile[4 * n4 + 1][c] = v.y;
            tile[4 * n4 + 2][c] = v.z; tile[4 * n4 + 3][c] = v.w;
        }
        __syncthreads();
        for (int i = 0; i < 4; ++i) {
            int idx = i * 256 + t; int n = idx >> 4, cg = idx & 15;
            short4_t pk;
            pk[0] = (short)f2bf(tile[n][4 * cg + 0]);
            pk[1] = (short)f2bf(tile[n][4 * cg + 1]);
            pk[2] = (short)f2bf(tile[n][4 * cg + 2]);
            pk[3] = (short)f2bf(tile[n][4 * cg + 3]);
            *(short4_t*)&dst[(long)(n0 + n) * 256 + c0 + 4 * cg] = pk;
        }
    } else if (blk < 56) {
        long g0 = (long)(blk - 40) * 16384;
        for (int i = 0; i < 16; ++i) {
            long e = g0 + (long)(i * 256 + t) * 4;
            int l = (int)(e >> 16); int off = (int)(e & 65535);
            const float* s = (l == 0) ? Wv0 : (l == 1) ? Wv1 : (l == 2) ? Wv2 : Wv3;
            float4 v = *(const float4*)&s[off];
            short4_t pk;
            pk[0] = (short)f2bf(v.x); pk[1] = (short)f2bf(v.y);
            pk[2] = (short)f2bf(v.z); pk[3] = (short)f2bf(v.w);
            *(short4_t*)&wv[e] = pk;
        }
    } else {
        // zero 128KB guard zones: 4 blocks each, 32768 B/block = 8 iters x 4096 B
        uint4 z = {0u, 0u, 0u, 0u};
        int sub = (blk - 56) & 3;
        uint4* g = (blk < 60) ? guard_lo : guard_hi;
        g += (long)sub * 2048 + t;   // uint4 units: 32768/16 = 2048 per block
        for (int i = 0; i < 8; ++i) g[i * 256] = z;
    }
}

// ---------------- K1a: qproj GEMM only. M=32768, N=384, K=256 -> gout f32[32768][384]
__global__ __launch_bounds__(256) void qproj_gemm(
    const float* __restrict__ query,
    const unsigned short* __restrict__ wq,
    float* __restrict__ gout)
{
    __shared__ unsigned short aT[64 * LPAD];
    __shared__ unsigned short bT[384 * LPAD];
    const int t = threadIdx.x;
    const int r0 = blockIdx.x * 64;
    const int w = t >> 6, lane = t & 63, quad = lane >> 4, l15 = lane & 15;

    floatx4 acc[24];
#pragma unroll
    for (int i = 0; i < 24; ++i) acc[i] = (floatx4){0.f, 0.f, 0.f, 0.f};

    for (int k0 = 0; k0 < 256; k0 += 32) {
        __syncthreads();
        for (int i = 0; i < 2; ++i) {  // A: query 64x32 fp32 -> bf16 (512 float4)
            int idx = i * 256 + t; int row = idx >> 3, kq = idx & 7;
            float4 v = *(const float4*)&query[(long)(r0 + row) * 256 + k0 + 4 * kq];
            short4_t pk;
            pk[0] = (short)f2bf(v.x); pk[1] = (short)f2bf(v.y);
            pk[2] = (short)f2bf(v.z); pk[3] = (short)f2bf(v.w);
            *(short4_t*)&aT[row * LPAD + 4 * kq] = pk;
        }
        for (int i = 0; i < 6; ++i) {  // B: wqT 384x32 bf16 (1536 uint4)
            int idx = i * 256 + t; int n = idx >> 2, kq = idx & 3;
            uint4 v = *(const uint4*)&wq[(long)n * 256 + k0 + 8 * kq];
            *(uint4*)&bT[n * LPAD + 8 * kq] = v;
        }
        __syncthreads();
        short8_t a8 = *(const short8_t*)&aT[(16 * w + l15) * LPAD + 8 * quad];
#pragma unroll
        for (int j = 0; j < 24; ++j) {
            short8_t b8 = *(const short8_t*)&bT[(16 * j + l15) * LPAD + 8 * quad];
            acc[j] = MFMA16(a8, b8, acc[j]);
        }
    }

    const int rbase = r0 + 16 * w + 4 * quad;
#pragma unroll
    for (int j = 0; j < 24; ++j) {
#pragma unroll
        for (int g = 0; g < 4; ++g)
            gout[(long)(rbase + g) * 384 + 16 * j + l15] = acc[j][g];
    }
}

// ---------------- K1b: setup. 1 thread per (r,h): reg softmax + tanh + pack sinfo.
// sinfo encoding: word0 = u16(i00 signed) | f2bf(X0)<<16
//                 word1 = f2bf(X1) | (wy14 | vy0<<14 | vy1<<15)<<16
// X0=a*(1-wx)*vx0, X1=a*wx*vx1, i00 = rowb + y0*Wl + x0 (unclamped). Fully-invalid
// points emit {0,0} so K3 reads stay within the guarded zones.
__global__ __launch_bounds__(256) void setup_kernel(
    const float* __restrict__ gout, const float* __restrict__ refp,
    const float* __restrict__ b_off, const float* __restrict__ b_attn,
    uint2* __restrict__ sinfo)
{
    const int t = threadIdx.x;
    const int h = t & 7;
    const int r = blockIdx.x * 32 + (t >> 3);
    const float* gl = gout + (long)r * 384;

    // softmax over the 16 attn logits (in registers, no cross-lane ops)
    float a[16];
    float m = -1e30f;
#pragma unroll
    for (int k = 0; k < 16; ++k) {
        a[k] = gl[256 + h * 16 + k] + b_attn[h * 16 + k];
        m = fmaxf(m, a[k]);
    }
    float s = 0.f;
#pragma unroll
    for (int k = 0; k < 16; ++k) { a[k] = __expf(a[k] - m); s += a[k]; }
    const float inv = 1.f / s;

    float off[32];
#pragma unroll
    for (int k = 0; k < 32; ++k) off[k] = gl[h * 32 + k] + b_off[h * 32 + k];
    const float rx = refp[(long)r * 2], ry = refp[(long)r * 2 + 1];

    uint2 pk[16];
#pragma unroll
    for (int k = 0; k < 16; ++k) {
        const int l = k >> 2;
        const int Wl = 128 >> l;
        const float dim1 = (float)(Wl - 1);
        const float scale = 2.0f * (float)(1 << l);
        const int rowb = (l == 0) ? 0 : (l == 1) ? 16384 : (l == 2) ? 20480 : 21504;
        float x = rx * dim1 + tanhf(off[2 * k]) * scale;
        float y = ry * dim1 + tanhf(off[2 * k + 1]) * scale;
        float fx = floorf(x), fy = floorf(y);
        int x0 = (int)fx, y0 = (int)fy;
        float wx = x - fx, wy = y - fy;
        bool vx0 = (x0 >= 0) && (x0 < Wl);
        bool vx1 = (x0 >= -1) && (x0 < Wl - 1);
        bool vy0 = (y0 >= 0) && (y0 < Wl);
        bool vy1 = (y0 >= -1) && (y0 < Wl - 1);
        if ((vx0 | vx1) & (vy0 | vy1)) {
            float av = a[k] * inv;
            float X0 = vx0 ? av * (1.f - wx) : 0.f;
            float X1 = vx1 ? av * wx : 0.f;
            int i00 = rowb + y0 * Wl + x0;           // signed, fits i16
            int wy14 = (int)(wy * 16384.f);          // [0,16383]
            unsigned int ypack = (unsigned int)wy14
                               | (vy0 ? 0x4000u : 0u) | (vy1 ? 0x8000u : 0u);
            pk[k].x = ((unsigned int)i00 & 0xffffu) | ((unsigned int)f2bf(X0) << 16);
            pk[k].y = (unsigned int)f2bf(X1) | (ypack << 16);
        } else {
            pk[k].x = 0u; pk[k].y = 0u;
        }
    }
    uint4* dst = (uint4*)(sinfo + ((long)r * 8 + h) * 16);
    const uint4* src = (const uint4*)pk;
#pragma unroll
    for (int i = 0; i < 8; ++i) dst[i] = src[i];
}

// ---------------- K2: vproj MFMA. 512 threads (8 waves), tile 128o x 256s.
// A(Wv half) staged ONCE into LDS (264-short rows, 16B-aligned). Wave w owns TWO
// s-strips (s0+16w, s0+128+16w) sharing each a8 read -> 16 MFMA + 16 global loads
// per k-step per wave. feat global->reg 1-step prefetch; NO barriers in k-loop.
__global__ __launch_bounds__(512) void vproj_mfma(
    const float* __restrict__ feat0, const float* __restrict__ feat1,
    const float* __restrict__ feat2, const float* __restrict__ feat3,
    const unsigned short* __restrict__ wv,
    const float* __restrict__ bv0, const float* __restrict__ bv1,
    const float* __restrict__ bv2, const float* __restrict__ bv3,
    unsigned short* __restrict__ vbuf)
{
    __shared__ unsigned short aW[128 * 264];   // 67,584 B
    const int blk = blockIdx.x;
    const int b = blk / 170;
    const int r = blk % 170;
    const float* feat; const unsigned short* wvl; const float* bvl; int S; long loff; int til;
    if (r < 128)      { til = r;       feat = feat0; wvl = wv;          bvl = bv0; S = 16384; loff = 0; }
    else if (r < 160) { til = r - 128; feat = feat1; wvl = wv + 65536;  bvl = bv1; S = 4096;  loff = 4194304; }
    else if (r < 168) { til = r - 160; feat = feat2; wvl = wv + 131072; bvl = bv2; S = 1024;  loff = 5242880; }
    else              { til = r - 168; feat = feat3; wvl = wv + 196608; bvl = bv3; S = 256;   loff = 5505024; }
    const int s0 = (til >> 1) * 256;
    const int o0 = (til & 1) * 128;
    const long fb = (long)b * 256 * S;
    const int t = threadIdx.x;
    const int w = t >> 6, lane = t & 63, quad = lane >> 4, l15 = lane & 15;

    // ---- stage A once: Wv[o0+o][k] -> aW[o*264 + k]  (4096 uint4, 8/thread)
    for (int i = 0; i < 8; ++i) {
        int idx = i * 512 + t;
        int o = idx >> 5, c8 = idx & 31;
        uint4 v = *(const uint4*)&wvl[(long)(o0 + o) * 256 + 8 * c8];
        *(uint4*)&aW[o * 264 + 8 * c8] = v;
    }
    __syncthreads();

    // ---- k-loop: two s-strips per wave, B direct from global, 1-step prefetch
    const long sbA = fb + s0 + 16 * w + l15;
    const long sbB = sbA + 128;
    float bcA[8], bcB[8], bnA[8], bnB[8];
#pragma unroll
    for (int i = 0; i < 8; ++i) {
        bcA[i] = feat[sbA + (long)(8 * quad + i) * S];
        bcB[i] = feat[sbB + (long)(8 * quad + i) * S];
    }

    floatx4 accA[8], accB[8];
#pragma unroll
    for (int i = 0; i < 8; ++i) {
        accA[i] = (floatx4){0.f, 0.f, 0.f, 0.f};
        accB[i] = (floatx4){0.f, 0.f, 0.f, 0.f};
    }

    for (int kt = 0; kt < 8; ++kt) {
        if (kt < 7) {
#pragma unroll
            for (int i = 0; i < 8; ++i) {
                bnA[i] = feat[sbA + (long)((kt + 1) * 32 + 8 * quad + i) * S];
                bnB[i] = feat[sbB + (long)((kt + 1) * 32 + 8 * quad + i) * S];
            }
        }
        short8_t b8A, b8B;
#pragma unroll
        for (int i = 0; i < 8; ++i) {
            b8A[i] = (short)f2bf(bcA[i]);
            b8B[i] = (short)f2bf(bcB[i]);
        }
#pragma unroll
        for (int mi = 0; mi < 8; ++mi) {
            short8_t a8 = *(const short8_t*)&aW[(16 * mi + l15) * 264 + 32 * kt + 8 * quad];
            accA[mi] = MFMA16(a8, b8A, accA[mi]);
            accB[mi] = MFMA16(a8, b8B, accB[mi]);
        }
#pragma unroll
        for (int i = 0; i < 8; ++i) { bcA[i] = bnA[i]; bcB[i] = bnB[i]; }
    }

    unsigned short* vb = vbuf + (long)b * 5570560 + loff;
    const int sA = s0 + 16 * w + l15;
#pragma unroll
    for (int mi = 0; mi < 8; ++mi) {
        int obase = o0 + 16 * mi + 4 * quad;
        float4 bias = *(const float4*)&bvl[obase];
        short4_t pkA, pkB;
        pkA[0] = (short)f2bf(accA[mi][0] + bias.x);
        pkA[1] = (short)f2bf(accA[mi][1] + bias.y);
        pkA[2] = (short)f2bf(accA[mi][2] + bias.z);
        pkA[3] = (short)f2bf(accA[mi][3] + bias.w);
        pkB[0] = (short)f2bf(accB[mi][0] + bias.x);
        pkB[1] = (short)f2bf(accB[mi][1] + bias.y);
        pkB[2] = (short)f2bf(accB[mi][2] + bias.z);
        pkB[3] = (short)f2bf(accB[mi][3] + bias.w);
        *(short4_t*)&vb[(long)sA * 256 + obase] = pkA;
        *(short4_t*)&vb[(long)(sA + 128) * 256 + obase] = pkB;
    }
}

// ---------------- K3: bilinear sampling, precomputed separable weights.
// 8 rows/block; lane owns 8 d-channels -> uint4 gathers (16B; 128B per 4-lane tap).
// Stray (zero-weight) reads are bounded to the zeroed guard zones or finite vbuf data.
__global__ __launch_bounds__(256) void sample_kernel(
    const uint2* __restrict__ sinfo,
    const unsigned short* __restrict__ vbuf,
    unsigned short* __restrict__ preb)
{
    const int t = threadIdx.x;
    const int dq = t & 3;           // d = 8*dq .. 8*dq+7
    const int h = (t >> 2) & 7;
    const int rsub = t >> 5;        // 8 rows per block
    const int r = blockIdx.x * 8 + rsub;
    const int b = r >> 12;

    const uint2* info = sinfo + ((long)r * 8 + h) * 16;
    const unsigned short* V = vbuf + (long)b * 5570560 + h * 32 + 8 * dq;

    float o0 = 0.f, o1 = 0.f, o2 = 0.f, o3 = 0.f;
    float o4 = 0.f, o5 = 0.f, o6 = 0.f, o7 = 0.f;
#define ACC8(gg, aw) \
    o0 += __uint_as_float(gg.x << 16) * aw;          \
    o1 += __uint_as_float(gg.x & 0xffff0000u) * aw;  \
    o2 += __uint_as_float(gg.y << 16) * aw;          \
    o3 += __uint_as_float(gg.y & 0xffff0000u) * aw;  \
    o4 += __uint_as_float(gg.z << 16) * aw;          \
    o5 += __uint_as_float(gg.z & 0xffff0000u) * aw;  \
    o6 += __uint_as_float(gg.w << 16) * aw;          \
    o7 += __uint_as_float(gg.w & 0xffff0000u) * aw;
#pragma unroll
    for (int k = 0; k < 16; ++k) {
        const int l = k >> 2;
        const int Wl = 128 >> l;
        uint2 inf = info[k];
        int i00 = (int)(short)(inf.x & 0xffffu);     // sign-extend
        float X0 = __uint_as_float(inf.x & 0xffff0000u);
        float X1 = __uint_as_float(inf.y << 16);
        unsigned int yp = inf.y >> 16;
        float wy = (float)(yp & 0x3fffu) * (1.f / 16384.f);
        float Y1 = (yp & 0x8000u) ? wy : 0.f;
        float Y0 = (yp & 0x4000u) ? (1.f - wy) : 0.f;
        const unsigned short* b00 = V + (long)i00 * 256;
        const unsigned short* b10 = b00 + Wl * 256;
        uint4 g00 = *(const uint4*)(b00);
        uint4 g01 = *(const uint4*)(b00 + 256);
        uint4 g10 = *(const uint4*)(b10);
        uint4 g11 = *(const uint4*)(b10 + 256);
        float aw00 = X0 * Y0, aw01 = X1 * Y0, aw10 = X0 * Y1, aw11 = X1 * Y1;
        ACC8(g00, aw00); ACC8(g01, aw01); ACC8(g10, aw10); ACC8(g11, aw11);
    }
#undef ACC8
    short8_t pk;
    pk[0] = (short)f2bf(o0); pk[1] = (short)f2bf(o1);
    pk[2] = (short)f2bf(o2); pk[3] = (short)f2bf(o3);
    pk[4] = (short)f2bf(o4); pk[5] = (short)f2bf(o5);
    pk[6] = (short)f2bf(o6); pk[7] = (short)f2bf(o7);
    *(short8_t*)&preb[(long)r * 256 + h * 32 + 8 * dq] = pk;
}

// ---------------- K4: outproj MFMA. D[j][r]; coalesced float4 stores.
__global__ __launch_bounds__(256) void outproj_mfma(
    const unsigned short* __restrict__ preb,
    const unsigned short* __restrict__ wo,
    const float* __restrict__ b_out,
    float* __restrict__ out)
{
    __shared__ unsigned short aJ[256 * LPAD];
    __shared__ unsigned short bR[64 * LPAD];
    const int t = threadIdx.x;
    const int r0 = blockIdx.x * 64;
    const int w = t >> 6, lane = t & 63, quad = lane >> 4, l15 = lane & 15;

    floatx4 acc[4][4];
#pragma unroll
    for (int i = 0; i < 4; ++i)
#pragma unroll
        for (int j = 0; j < 4; ++j) acc[i][j] = (floatx4){0.f, 0.f, 0.f, 0.f};

    for (int k0 = 0; k0 < 256; k0 += 32) {
        __syncthreads();
        for (int i = 0; i < 4; ++i) {  // A: woT 256 rows x 32k = 1024 uint4
            int idx = i * 256 + t; int j = idx >> 2, kq = idx & 3;
            uint4 v = *(const uint4*)&wo[(long)j * 256 + k0 + 8 * kq];
            *(uint4*)&aJ[j * LPAD + 8 * kq] = v;
        }
        {   // B: preb 64 rows x 32k = 256 uint4
            int rr = t >> 2, kq = t & 3;
            uint4 v = *(const uint4*)&preb[(long)(r0 + rr) * 256 + k0 + 8 * kq];
            *(uint4*)&bR[rr * LPAD + 8 * kq] = v;
        }
        __syncthreads();
        short8_t am[4];
#pragma unroll
        for (int mi = 0; mi < 4; ++mi)
            am[mi] = *(const short8_t*)&aJ[(64 * w + 16 * mi + l15) * LPAD + 8 * quad];
#pragma unroll
        for (int nj = 0; nj < 4; ++nj) {
            short8_t b8 = *(const short8_t*)&bR[(16 * nj + l15) * LPAD + 8 * quad];
#pragma unroll
            for (int mi = 0; mi < 4; ++mi)
                acc[mi][nj] = MFMA16(am[mi], b8, acc[mi][nj]);
        }
    }

#pragma unroll
    for (int mi = 0; mi < 4; ++mi) {
        int j0 = 64 * w + 16 * mi + 4 * quad;
        float4 bias = *(const float4*)&b_out[j0];
#pragma unroll
        for (int nj = 0; nj < 4; ++nj) {
            int r = r0 + 16 * nj + l15;
            float4 res;
            res.x = acc[mi][nj][0] + bias.x;
            res.y = acc[mi][nj][1] + bias.y;
            res.z = acc[mi][nj][2] + bias.z;
            res.w = acc[mi][nj][3] + bias.w;
            *(float4*)&out[(long)r * 256 + j0] = res;
        }
    }
}

extern "C" void kernel_launch(void* const* d_in, const int* in_sizes, int n_in,
                              void* d_out, int out_size, void* d_ws, size_t ws_size,
                              hipStream_t stream) {
    const float* query  = (const float*)d_in[0];
    const float* refp   = (const float*)d_in[1];
    const float* feat0  = (const float*)d_in[2];
    const float* feat1  = (const float*)d_in[3];
    const float* feat2  = (const float*)d_in[4];
    const float* feat3  = (const float*)d_in[5];
    const float* W_off  = (const float*)d_in[6];
    const float* b_off  = (const float*)d_in[7];
    const float* W_attn = (const float*)d_in[8];
    const float* b_attn = (const float*)d_in[9];
    const float* Wv0 = (const float*)d_in[10]; const float* bv0 = (const float*)d_in[11];
    const float* Wv1 = (const float*)d_in[12]; const float* bv1 = (const float*)d_in[13];
    const float* Wv2 = (const float*)d_in[14]; const float* bv2 = (const float*)d_in[15];
    const float* Wv3 = (const float*)d_in[16]; const float* bv3 = (const float*)d_in[17];
    const float* W_out = (const float*)d_in[18]; const float* b_out = (const float*)d_in[19];
    float* out = (float*)d_out;

    char* ws = (char*)d_ws;
    uint2*          sinfo = (uint2*)(ws + 0);
    uint4*          guard_lo = (uint4*)(ws + 33554432);
    unsigned short* vbuf = (unsigned short*)(ws + 33685504);
    float*          gout = (float*)(ws + 33685504);   // overlaps vbuf (dead until vproj)
    uint4*          guard_hi = (uint4*)(ws + 122814464);
    unsigned short* preb = (unsigned short*)(ws + 122945536);
    unsigned short* wq   = (unsigned short*)(ws + 139722752);
    unsigned short* wv   = (unsigned short*)(ws + 139919360);
    unsigned short* wo   = (unsigned short*)(ws + 140443648);

    prep_kernel<<<64, 256, 0, stream>>>(W_off, W_attn, Wv0, Wv1, Wv2, Wv3, W_out,
                                        wq, wv, wo, guard_lo, guard_hi);
    qproj_gemm<<<512, 256, 0, stream>>>(query, wq, gout);
    setup_kernel<<<1024, 256, 0, stream>>>(gout, refp, b_off, b_attn, sinfo);
    vproj_mfma<<<1360, 512, 0, stream>>>(feat0, feat1, feat2, feat3, wv,
                                         bv0, bv1, bv2, bv3, vbuf);
    sample_kernel<<<4096, 256, 0, stream>>>(sinfo, vbuf, preb);
    outproj_mfma<<<512, 256, 0, stream>>>(preb, wo, b_out, out);
}